// Round 14
// baseline (286.355 us; speedup 1.0000x reference)
//
#include <hip/hip_runtime.h>
#include <hip/hip_bf16.h>

// ---------- problem constants ----------
#define BATCH   2
#define SEQ     2048
#define DMODEL  1024
#define NHEADS  16
#define DHEAD   64
#define MROWS   (BATCH*SEQ)     // 4096
#define NBH     (BATCH*NHEADS)  // 32

typedef float  f32x4  __attribute__((ext_vector_type(4)));
typedef short  s16x4  __attribute__((ext_vector_type(4)));
typedef short  s16x8  __attribute__((ext_vector_type(8)));
typedef __bf16 bf16x8 __attribute__((ext_vector_type(8)));

__device__ __forceinline__ short f2bf(float f) {
  union { float f; unsigned u; } v; v.f = f;
  return (short)((v.u + 0x7fffu + ((v.u >> 16) & 1u)) >> 16);  // RNE
}
__device__ __forceinline__ float bf2f(short s) {
  union { unsigned u; float f; } v; v.u = ((unsigned)(unsigned short)s) << 16;
  return v.f;
}

// ---------- fused prep: z<4 -> W transpose+bf16; z>=4 -> x fp32->bf16 -------
__global__ void prep_fused(const float* __restrict__ x, short* __restrict__ xb,
                           const float* __restrict__ Wq, const float* __restrict__ Wk,
                           const float* __restrict__ Wv, const float* __restrict__ Wo,
                           short* __restrict__ WtQKV, short* __restrict__ WtO) {
  __shared__ float t[32][33];
  int z = blockIdx.z;
  int tx = threadIdx.x, ty = threadIdx.y;           // block (32,8)
  if (z >= 4) {                                     // convert x chunk
    int blk = (z - 4) * 1024 + blockIdx.y * 32 + blockIdx.x;
    int i = (blk * 256 + ty * 32 + tx) * 4;
    float4 v = *(const float4*)(x + i);
    s16x4 o = { f2bf(v.x), f2bf(v.y), f2bf(v.z), f2bf(v.w) };
    *(s16x4*)(xb + i) = o;
    return;
  }
  const float* W; short* Wt;
  if      (z == 0) { W = Wq; Wt = WtQKV; }
  else if (z == 1) { W = Wk; Wt = WtQKV + (1u << 20); }
  else if (z == 2) { W = Wv; Wt = WtQKV + (2u << 20); }
  else             { W = Wo; Wt = WtO; }
  int n0 = blockIdx.x * 32, k0 = blockIdx.y * 32;
  #pragma unroll
  for (int i = 0; i < 32; i += 8) t[ty + i][tx] = W[(k0 + ty + i) * DMODEL + n0 + tx];
  __syncthreads();
  #pragma unroll
  for (int i = 0; i < 32; i += 8) Wt[(n0 + ty + i) * DMODEL + k0 + tx] = f2bf(t[tx][ty + i]);
}

// ---------- bf16 GEMM, m97 single-slab BK=32 + XCD-band swizzle (R13) --------
template<int MT, int NT, int EPI>
__global__ __launch_bounds__(256) void gemm_bf16(
    const short* __restrict__ A, const short* __restrict__ Bt,
    const float* __restrict__ bq, const float* __restrict__ bk, const float* __restrict__ bv,
    short* __restrict__ qb, short* __restrict__ kb, short* __restrict__ vt,
    float* __restrict__ out)
{
  constexpr int K = DMODEL, BK = 32;
  constexpr int WM = MT / 2, WN = NT / 2;
  constexpr int TM = WM / 16, TN = WN / 16;
  constexpr int CA = MT * BK / 512;
  constexpr int CB = NT * BK / 512;
  constexpr int TP = 136;                            // epilogue tile pitch (shorts)
  constexpr int SME = (EPI == 0) ? 128 * TP : (MT * BK + NT * BK);
  __shared__ short smem[SME];
  short* la = smem;
  short* lb = smem + MT * BK;
  const int tid = threadIdx.x;
  const int wave = tid >> 6, lane = tid & 63;
  const int quad = lane >> 4, l16 = lane & 15;
  const int wr = wave >> 1, wc = wave & 1;
  // XCD-band swizzle (gridDim.y % 8 == 0): each XCD owns a contiguous m-band
  const int nx = gridDim.x, ny = gridDim.y;
  const int g = blockIdx.y * nx + blockIdx.x;
  const int xcd = g & 7, rr = g >> 3;
  const int m0 = (xcd * (ny >> 3) + rr / nx) * MT;
  const int n0 = (rr % nx) * NT;
  const int arow = lane >> 2, acol = (lane & 3) * 8;

  f32x4 acc[TM][TN] = {};

  for (int k0 = 0; k0 < K; k0 += BK) {
    for (int c = wave; c < CA; c += 4) {
      const short* gp = A + (m0 + c * 16 + arow) * K + k0 + acol;
      __builtin_amdgcn_global_load_lds((__attribute__((address_space(1))) void*)gp,
                                       (__attribute__((address_space(3))) void*)(la + c * 512),
                                       16, 0, 0);
    }
    for (int c = wave; c < CB; c += 4) {
      const short* gp = Bt + (n0 + c * 16 + arow) * K + k0 + acol;
      __builtin_amdgcn_global_load_lds((__attribute__((address_space(1))) void*)gp,
                                       (__attribute__((address_space(3))) void*)(lb + c * 512),
                                       16, 0, 0);
    }
    __syncthreads();
    bf16x8 af[TM], bfr[TN];
    #pragma unroll
    for (int i = 0; i < TM; ++i)
      af[i] = *(const bf16x8*)&la[(wr * WM + i * 16 + l16) * BK + quad * 8];
    #pragma unroll
    for (int j = 0; j < TN; ++j)
      bfr[j] = *(const bf16x8*)&lb[(wc * WN + j * 16 + l16) * BK + quad * 8];
    #pragma unroll
    for (int i = 0; i < TM; ++i)
      #pragma unroll
      for (int j = 0; j < TN; ++j)
        acc[i][j] = __builtin_amdgcn_mfma_f32_16x16x32_bf16(af[i], bfr[j], acc[i][j], 0, 0, 0);
    __syncthreads();
  }

  if constexpr (EPI == 0) {
    const bool isV = (n0 >= 2 * DMODEL);
    const float* bias; int nbase; float scl;
    // Q scale folds 1/sqrt(Dh) AND log2(e) so attention uses exp2 directly.
    if (n0 < DMODEL)          { bias = bq; nbase = 0;          scl = 0.125f * 1.44269504089f; }
    else if (n0 < 2 * DMODEL) { bias = bk; nbase = DMODEL;     scl = 1.f; }
    else                      { bias = bv; nbase = 2 * DMODEL; scl = 1.f; }
    #pragma unroll
    for (int j = 0; j < TN; ++j) {
      int coll = wc * WN + j * 16 + l16;
      float bias_v = bias[n0 - nbase + coll];
      #pragma unroll
      for (int i = 0; i < TM; ++i) {
        int rowl = wr * WM + i * 16 + quad * 4;
        #pragma unroll
        for (int r = 0; r < 4; ++r) {
          short v = f2bf((acc[i][j][r] + bias_v) * scl);
          if (isV) smem[coll * TP + rowl + r] = v;   // transposed for V
          else     smem[(rowl + r) * TP + coll] = v;
        }
      }
    }
    __syncthreads();
    const int b = m0 >> 11, s0 = m0 & (SEQ - 1);
    const int rseg = tid & 15, rrow = tid >> 4;
    if (!isV) {
      short* dst = (n0 < DMODEL) ? qb : kb;
      #pragma unroll
      for (int it = 0; it < 8; ++it) {
        int row = it * 16 + rrow;
        int colg = (n0 - nbase) + rseg * 8;
        int h = colg >> 6, d = colg & 63;
        s16x8 v = *(const s16x8*)&smem[row * TP + rseg * 8];
        *(s16x8*)(dst + ((b * NHEADS + h) * SEQ + s0 + row) * DHEAD + d) = v;
      }
    } else {
      #pragma unroll
      for (int it = 0; it < 8; ++it) {
        int drow = it * 16 + rrow;
        int colg = (n0 - nbase) + drow;
        int h = colg >> 6, d = colg & 63;
        s16x8 v = *(const s16x8*)&smem[drow * TP + rseg * 8];
        *(s16x8*)(vt + ((b * NHEADS + h) * DHEAD + d) * SEQ + s0 + rseg * 8) = v;
      }
    }
  } else {
    #pragma unroll
    for (int i = 0; i < TM; ++i)
      #pragma unroll
      for (int r = 0; r < 4; ++r) {
        int mrow = m0 + wr * WM + i * 16 + quad * 4 + r;
        #pragma unroll
        for (int j = 0; j < TN; ++j)
          out[mrow * DMODEL + n0 + wc * WN + j * 16 + l16] = acc[i][j][r];
      }
    (void)bq; (void)bk; (void)bv; (void)qb; (void)kb; (void)vt;
  }
}

// ================= flash attention v9: fused last-finisher merge ==============
// R13 lesson: kernel-internal wins are masked by serial launch structure ->
// remove a launch. Both halves of (qg,bh) write partials, release-fence, bump
// a flag; the SECOND finisher acquire-fences and merges using its register
// copy + the other half's global partials, writing final ob (merge lands in
// the tail slack). Pair-balance swizzle: co-resident pair (b, b+256) gets
// (qg, 7-qg) -> every CU carries exactly 25 chunk-units (was 22..28).

__global__ __launch_bounds__(256, 2) void attn_k(
    const short* __restrict__ qbp, const short* __restrict__ kbp,
    const short* __restrict__ vtb, short* __restrict__ oP, float* __restrict__ lP,
    short* __restrict__ ob, int* __restrict__ flags)
{
  __shared__ short kls[2][8192];                    // 2 bufs x (2 chunks x 8KB)
  __shared__ short vls[2][8192];
  const int tid = threadIdx.x, wave = tid >> 6, lane = tid & 63;
  const int quad = lane >> 4, l16 = lane & 15;
  // pair-balance decode: b and b+256 -> same CU (heuristic), qg + qg' = 7
  const int half = blockIdx.x >> 8;
  const int r8 = blockIdx.x & 255;
  const int qg = half ? 7 - (r8 >> 5) : (r8 >> 5);  // 0..7
  const int bh = r8 & 31;
  const int qt1 = qg * 8 + wave * 2;                // 0..62 even
  const int mF[4] = { qt1 * 16, (qt1 + 1) * 16, (126 - qt1) * 16, (127 - qt1) * 16 };
  const int nch = (127 - 8 * qg) / 4 + 1;          // block-uniform chunk count
  const short* Q  = qbp + bh * SEQ * DHEAD;
  const short* Kp = kbp + bh * SEQ * DHEAD;
  const short* Vt = vtb + bh * DHEAD * SEQ;

  bf16x8 qf[4][2];
  #pragma unroll
  for (int f = 0; f < 4; ++f) {
    qf[f][0] = *(const bf16x8*)&Q[(mF[f] + l16) * DHEAD + quad * 8];
    qf[f][1] = *(const bf16x8*)&Q[(mF[f] + l16) * DHEAD + 32 + quad * 8];
  }

  float lF[4] = {};
  f32x4 oF[4][4] = {};

  const int vdl = lane >> 3, vsl = lane & 7;        // V staging lane split

  auto stage1 = [&](int buf, int slot, int t0) {    // one 64-t chunk
    #pragma unroll
    for (int j = 0; j < 2; ++j) {
      int g = j * 4 + wave;                         // K ch-group 0..7
      const short* gp = Kp + (t0 + lane) * DHEAD + g * 8;
      __builtin_amdgcn_global_load_lds((__attribute__((address_space(1))) void*)gp,
                                       (__attribute__((address_space(3))) void*)&kls[buf][slot * 4096 + g * 512],
                                       16, 0, 0);
    }
    #pragma unroll
    for (int j = 0; j < 2; ++j) {
      int gd = j * 4 + wave;                        // V d-block 0..7
      const short* gp = Vt + (gd * 8 + vdl) * SEQ + t0 + ((vsl ^ vdl) * 8);
      __builtin_amdgcn_global_load_lds((__attribute__((address_space(1))) void*)gp,
                                       (__attribute__((address_space(3))) void*)&vls[buf][slot * 4096 + gd * 512],
                                       16, 0, 0);
    }
  };
  auto stagepair = [&](int buf, int cc) {           // chunks cc, cc+2 (owned set)
    stage1(buf, 0, cc * 64);
    if (cc + 2 < nch) stage1(buf, 1, (cc + 2) * 64);
  };

  stagepair(0, half);
  int it = 0;
  for (int cc = half; cc < nch; cc += 4, ++it) {
    __syncthreads();                                // drains stagepair; waves synced
    if (cc + 4 < nch) stagepair((it + 1) & 1, cc + 4);
    const int buf = it & 1;
    #pragma unroll
    for (int u = 0; u < 2; ++u) {                   // chunk within pair
      const int c = cc + 2 * u;
      if (c < nch) {                                // block-uniform
        const int t0 = c * 64;
        const int sb = u * 4096;
        #pragma unroll
        for (int t = 0; t < 4; ++t) {
          const int tb = t0 + t * 16;
          if (tb <= mF[3]) {                        // any fragment live (wave-uniform)
            bf16x8 kf0 = *(const bf16x8*)&kls[buf][sb + ((0 + quad) * 64 + t * 16 + l16) * 8];
            bf16x8 kf1 = *(const bf16x8*)&kls[buf][sb + ((4 + quad) * 64 + t * 16 + l16) * 8];
            s16x4 vf[4];
            {
              int gsw = ((t * 2 + (quad >> 1)) ^ (l16 & 7));
              #pragma unroll
              for (int dt = 0; dt < 4; ++dt)
                vf[dt] = *(const s16x4*)&vls[buf][sb + ((dt * 16 + l16) * 8 + gsw) * 8 + (quad & 1) * 4];
            }
            #pragma unroll
            for (int f = 0; f < 4; ++f) {
              if (tb <= mF[f]) {                    // wave-uniform
                f32x4 a = {};
                a = __builtin_amdgcn_mfma_f32_16x16x32_bf16(kf0, qf[f][0], a, 0, 0, 0);
                a = __builtin_amdgcn_mfma_f32_16x16x32_bf16(kf1, qf[f][1], a, 0, 0, 0);
                if (tb == mF[f]) {                  // diagonal: mask t > m
                  #pragma unroll
                  for (int r = 0; r < 4; ++r)
                    if (quad * 4 + r > l16) a[r] = -1e30f;
                }
                f32x4 p;
                #pragma unroll
                for (int r = 0; r < 4; ++r) p[r] = __builtin_amdgcn_exp2f(a[r]);
                lF[f] += (p[0] + p[1]) + (p[2] + p[3]);
                __hip_bfloat162 c01 = __float22bfloat162_rn(float2{p[0], p[1]});
                __hip_bfloat162 c23 = __float22bfloat162_rn(float2{p[2], p[3]});
                union { unsigned u2[2]; s16x4 s; } pu;
                pu.u2[0] = *(unsigned*)&c01; pu.u2[1] = *(unsigned*)&c23;
                #pragma unroll
                for (int dt = 0; dt < 4; ++dt)
                  oF[f][dt] = __builtin_amdgcn_mfma_f32_16x16x16bf16_1k(pu.s, vf[dt], oF[f][dt], 0, 0, 0);
              }
            }
          }
        }
      }
    }
  }

  // reduce l across quads; publish partials [half][bh][s][64]
  float* lD = lP + (half * NBH + bh) * SEQ;
  short* oD = oP + ((half * NBH + bh) * SEQ) * DHEAD;
  #pragma unroll
  for (int f = 0; f < 4; ++f) {
    float l = lF[f];
    l += __shfl_xor(l, 16, 64); l += __shfl_xor(l, 32, 64);
    lF[f] = l;                                      // keep reduced copy in regs
    if (quad == 0) lD[mF[f] + l16] = l;
    #pragma unroll
    for (int r = 0; r < 4; ++r) {
      int s = mF[f] + quad * 4 + r;
      #pragma unroll
      for (int dt = 0; dt < 4; ++dt)
        oD[s * DHEAD + dt * 16 + l16] = f2bf(oF[f][dt][r]);
    }
  }

  // ---- last-finisher merge (agent-scope release/acquire protocol) ----
  __threadfence();                                  // release: drain partial stores
  __syncthreads();
  __shared__ int win;
  if (tid == 0) win = (atomicAdd(&flags[qg * 32 + bh], 1) == 1);
  __syncthreads();
  if (!win) return;
  __threadfence();                                  // acquire: invalidate stale L2
  const int oh = 1 - half;
  const short* oO = oP + ((oh * NBH + bh) * SEQ) * DHEAD;
  const float* lO = lP + (oh * NBH + bh) * SEQ;
  const int b = bh >> 4, h = bh & 15;
  #pragma unroll
  for (int f = 0; f < 4; ++f) {
    #pragma unroll
    for (int r = 0; r < 4; ++r) {
      int s = mF[f] + quad * 4 + r;
      float lown = __shfl(lF[f], quad * 4 + r, 64);
      float linv = 1.0f / (lown + lO[s]);
      #pragma unroll
      for (int dt = 0; dt < 4; ++dt) {
        float other = bf2f(oO[s * DHEAD + dt * 16 + l16]);
        ob[(b * SEQ + s) * DMODEL + h * DHEAD + dt * 16 + l16] =
            f2bf((oF[f][dt][r] + other) * linv);
      }
    }
  }
}

extern "C" void kernel_launch(void* const* d_in, const int* in_sizes, int n_in,
                              void* d_out, int out_size, void* d_ws, size_t ws_size,
                              hipStream_t stream) {
  const float* x  = (const float*)d_in[0];
  const float* Wq = (const float*)d_in[1];
  const float* bq = (const float*)d_in[2];
  const float* Wk = (const float*)d_in[3];
  const float* bk = (const float*)d_in[4];
  const float* Wv = (const float*)d_in[5];
  const float* bv = (const float*)d_in[6];
  const float* Wo = (const float*)d_in[7];
  float* out = (float*)d_out;

  char* ws = (char*)d_ws;                         // ws is 256 MB (measured R7)
  short* xb  = (short*)(ws);                      // 8 MB  x bf16
  short* wtq = (short*)(ws + (8u  << 20));        // 6 MB  [Wq^T;Wk^T;Wv^T] bf16
  short* wto = (short*)(ws + (14u << 20));        // 2 MB  Wo^T bf16
  short* qb  = (short*)(ws + (16u << 20));        // 8 MB  Q (x 0.125*log2e folded)
  short* kb  = (short*)(ws + (24u << 20));        // 8 MB  K
  short* vt  = (short*)(ws + (32u << 20));        // 8 MB  V^T [bh][d][s]
  short* ob  = (short*)(ws + (40u << 20));        // 8 MB  attn out bf16
  short* oP  = (short*)(ws + (48u << 20));        // 16 MB o-partials [2][32][2048][64]
  float* lP  = (float*)(ws + (80u << 20));        // 0.5MB l-partials [2][32][2048]
  int*   flg = (int*)  (ws + (81u << 20));        // 1 KB  merge flags [8][32]

  hipMemsetAsync(flg, 0, 256 * sizeof(int), stream);

  prep_fused<<<dim3(32, 32, 8), dim3(32, 8), 0, stream>>>(x, xb, Wq, Wk, Wv, Wo, wtq, wto);

  gemm_bf16<128, 128, 0><<<dim3(3 * DMODEL / 128, MROWS / 128), 256, 0, stream>>>(
      xb, wtq, bq, bk, bv, qb, kb, vt, nullptr);

  attn_k<<<8 * NBH * 2, 256, 0, stream>>>(qb, kb, vt, oP, lP, ob, flg);

  gemm_bf16<64, 128, 1><<<dim3(DMODEL / 128, MROWS / 64), 256, 0, stream>>>(
      ob, wto, nullptr, nullptr, nullptr, nullptr, nullptr, nullptr, out);
}

// Round 15
// 185.041 us; speedup vs baseline: 1.5475x; 1.5475x over previous
//
#include <hip/hip_runtime.h>
#include <hip/hip_bf16.h>

// ---------- problem constants ----------
#define BATCH   2
#define SEQ     2048
#define DMODEL  1024
#define NHEADS  16
#define DHEAD   64
#define MROWS   (BATCH*SEQ)     // 4096
#define NBH     (BATCH*NHEADS)  // 32

typedef float  f32x4  __attribute__((ext_vector_type(4)));
typedef short  s16x4  __attribute__((ext_vector_type(4)));
typedef short  s16x8  __attribute__((ext_vector_type(8)));
typedef __bf16 bf16x8 __attribute__((ext_vector_type(8)));

__device__ __forceinline__ short f2bf(float f) {
  union { float f; unsigned u; } v; v.f = f;
  return (short)((v.u + 0x7fffu + ((v.u >> 16) & 1u)) >> 16);  // RNE
}
__device__ __forceinline__ float bf2f(short s) {
  union { unsigned u; float f; } v; v.u = ((unsigned)(unsigned short)s) << 16;
  return v.f;
}

// ---------- fused prep: z<4 -> W transpose+bf16; z>=4 -> x fp32->bf16 -------
__global__ void prep_fused(const float* __restrict__ x, short* __restrict__ xb,
                           const float* __restrict__ Wq, const float* __restrict__ Wk,
                           const float* __restrict__ Wv, const float* __restrict__ Wo,
                           short* __restrict__ WtQKV, short* __restrict__ WtO) {
  __shared__ float t[32][33];
  int z = blockIdx.z;
  int tx = threadIdx.x, ty = threadIdx.y;           // block (32,8)
  if (z >= 4) {                                     // convert x chunk
    int blk = (z - 4) * 1024 + blockIdx.y * 32 + blockIdx.x;
    int i = (blk * 256 + ty * 32 + tx) * 4;
    float4 v = *(const float4*)(x + i);
    s16x4 o = { f2bf(v.x), f2bf(v.y), f2bf(v.z), f2bf(v.w) };
    *(s16x4*)(xb + i) = o;
    return;
  }
  const float* W; short* Wt;
  if      (z == 0) { W = Wq; Wt = WtQKV; }
  else if (z == 1) { W = Wk; Wt = WtQKV + (1u << 20); }
  else if (z == 2) { W = Wv; Wt = WtQKV + (2u << 20); }
  else             { W = Wo; Wt = WtO; }
  int n0 = blockIdx.x * 32, k0 = blockIdx.y * 32;
  #pragma unroll
  for (int i = 0; i < 32; i += 8) t[ty + i][tx] = W[(k0 + ty + i) * DMODEL + n0 + tx];
  __syncthreads();
  #pragma unroll
  for (int i = 0; i < 32; i += 8) Wt[(n0 + ty + i) * DMODEL + k0 + tx] = f2bf(t[tx][ty + i]);
}

// ---------- bf16 GEMM, m97 single-slab BK=32 + XCD-band swizzle (R13) --------
template<int MT, int NT, int EPI>
__global__ __launch_bounds__(256) void gemm_bf16(
    const short* __restrict__ A, const short* __restrict__ Bt,
    const float* __restrict__ bq, const float* __restrict__ bk, const float* __restrict__ bv,
    short* __restrict__ qb, short* __restrict__ kb, short* __restrict__ vt,
    float* __restrict__ out)
{
  constexpr int K = DMODEL, BK = 32;
  constexpr int WM = MT / 2, WN = NT / 2;
  constexpr int TM = WM / 16, TN = WN / 16;
  constexpr int CA = MT * BK / 512;
  constexpr int CB = NT * BK / 512;
  constexpr int TP = 136;                            // epilogue tile pitch (shorts)
  constexpr int SME = (EPI == 0) ? 128 * TP : (MT * BK + NT * BK);
  __shared__ short smem[SME];
  short* la = smem;
  short* lb = smem + MT * BK;
  const int tid = threadIdx.x;
  const int wave = tid >> 6, lane = tid & 63;
  const int quad = lane >> 4, l16 = lane & 15;
  const int wr = wave >> 1, wc = wave & 1;
  // XCD-band swizzle (gridDim.y % 8 == 0): each XCD owns a contiguous m-band
  const int nx = gridDim.x, ny = gridDim.y;
  const int g = blockIdx.y * nx + blockIdx.x;
  const int xcd = g & 7, rr = g >> 3;
  const int m0 = (xcd * (ny >> 3) + rr / nx) * MT;
  const int n0 = (rr % nx) * NT;
  const int arow = lane >> 2, acol = (lane & 3) * 8;

  f32x4 acc[TM][TN] = {};

  for (int k0 = 0; k0 < K; k0 += BK) {
    for (int c = wave; c < CA; c += 4) {
      const short* gp = A + (m0 + c * 16 + arow) * K + k0 + acol;
      __builtin_amdgcn_global_load_lds((__attribute__((address_space(1))) void*)gp,
                                       (__attribute__((address_space(3))) void*)(la + c * 512),
                                       16, 0, 0);
    }
    for (int c = wave; c < CB; c += 4) {
      const short* gp = Bt + (n0 + c * 16 + arow) * K + k0 + acol;
      __builtin_amdgcn_global_load_lds((__attribute__((address_space(1))) void*)gp,
                                       (__attribute__((address_space(3))) void*)(lb + c * 512),
                                       16, 0, 0);
    }
    __syncthreads();
    bf16x8 af[TM], bfr[TN];
    #pragma unroll
    for (int i = 0; i < TM; ++i)
      af[i] = *(const bf16x8*)&la[(wr * WM + i * 16 + l16) * BK + quad * 8];
    #pragma unroll
    for (int j = 0; j < TN; ++j)
      bfr[j] = *(const bf16x8*)&lb[(wc * WN + j * 16 + l16) * BK + quad * 8];
    #pragma unroll
    for (int i = 0; i < TM; ++i)
      #pragma unroll
      for (int j = 0; j < TN; ++j)
        acc[i][j] = __builtin_amdgcn_mfma_f32_16x16x32_bf16(af[i], bfr[j], acc[i][j], 0, 0, 0);
    __syncthreads();
  }

  if constexpr (EPI == 0) {
    const bool isV = (n0 >= 2 * DMODEL);
    const float* bias; int nbase; float scl;
    // Q scale folds 1/sqrt(Dh) AND log2(e) so attention uses exp2 directly.
    if (n0 < DMODEL)          { bias = bq; nbase = 0;          scl = 0.125f * 1.44269504089f; }
    else if (n0 < 2 * DMODEL) { bias = bk; nbase = DMODEL;     scl = 1.f; }
    else                      { bias = bv; nbase = 2 * DMODEL; scl = 1.f; }
    #pragma unroll
    for (int j = 0; j < TN; ++j) {
      int coll = wc * WN + j * 16 + l16;
      float bias_v = bias[n0 - nbase + coll];
      #pragma unroll
      for (int i = 0; i < TM; ++i) {
        int rowl = wr * WM + i * 16 + quad * 4;
        #pragma unroll
        for (int r = 0; r < 4; ++r) {
          short v = f2bf((acc[i][j][r] + bias_v) * scl);
          if (isV) smem[coll * TP + rowl + r] = v;   // transposed for V
          else     smem[(rowl + r) * TP + coll] = v;
        }
      }
    }
    __syncthreads();
    const int b = m0 >> 11, s0 = m0 & (SEQ - 1);
    const int rseg = tid & 15, rrow = tid >> 4;
    if (!isV) {
      short* dst = (n0 < DMODEL) ? qb : kb;
      #pragma unroll
      for (int it = 0; it < 8; ++it) {
        int row = it * 16 + rrow;
        int colg = (n0 - nbase) + rseg * 8;
        int h = colg >> 6, d = colg & 63;
        s16x8 v = *(const s16x8*)&smem[row * TP + rseg * 8];
        *(s16x8*)(dst + ((b * NHEADS + h) * SEQ + s0 + row) * DHEAD + d) = v;
      }
    } else {
      #pragma unroll
      for (int it = 0; it < 8; ++it) {
        int drow = it * 16 + rrow;
        int colg = (n0 - nbase) + drow;
        int h = colg >> 6, d = colg & 63;
        s16x8 v = *(const s16x8*)&smem[drow * TP + rseg * 8];
        *(s16x8*)(vt + ((b * NHEADS + h) * DHEAD + d) * SEQ + s0 + rseg * 8) = v;
      }
    }
  } else {
    #pragma unroll
    for (int i = 0; i < TM; ++i)
      #pragma unroll
      for (int r = 0; r < 4; ++r) {
        int mrow = m0 + wr * WM + i * 16 + quad * 4 + r;
        #pragma unroll
        for (int j = 0; j < TN; ++j)
          out[mrow * DMODEL + n0 + wc * WN + j * 16 + l16] = acc[i][j][r];
      }
    (void)bq; (void)bk; (void)bv; (void)qb; (void)kb; (void)vt;
  }
}

// ================= flash attention v8r: R13 core + pair-balance decode ========
// R14 post-mortem: in-kernel last-finisher merge with __threadfence() thrashed
// L2 (agent-scope wb/inv while other blocks' K-loops were live) -> 3x slower.
// REVERTED to separate merge kernel. Kept (fence-free) from R14: pair-balance
// decode. All 512 blocks are exactly co-resident (2/CU); blocks g and g+256
// likely share a CU, so qg(g) + qg(g+256) == 7 equalizes per-CU chunk load
// (24 units vs 16..32 spread). Same-bh halves stay 32 apart -> same XCD L2.

__global__ __launch_bounds__(256, 2) void attn_k(
    const short* __restrict__ qbp, const short* __restrict__ kbp,
    const short* __restrict__ vtb, short* __restrict__ oP, float* __restrict__ lP)
{
  __shared__ short kls[2][8192];                    // 2 bufs x (2 chunks x 8KB)
  __shared__ short vls[2][8192];
  const int tid = threadIdx.x, wave = tid >> 6, lane = tid & 63;
  const int quad = lane >> 4, l16 = lane & 15;
  // pair-balance decode: qg = hi ? 7-q6 : q6  (bijective over 512 blocks)
  const int hi = blockIdx.x >> 8;
  const int q6 = (blockIdx.x >> 6) & 3;
  const int qg = hi ? 7 - q6 : q6;                  // 0..7
  const int half = (blockIdx.x >> 5) & 1;
  const int bh = blockIdx.x & 31;
  const int qt1 = qg * 8 + wave * 2;                // 0..62 even
  const int mF[4] = { qt1 * 16, (qt1 + 1) * 16, (126 - qt1) * 16, (127 - qt1) * 16 };
  const int nch = (127 - 8 * qg) / 4 + 1;          // block-uniform chunk count
  const short* Q  = qbp + bh * SEQ * DHEAD;
  const short* Kp = kbp + bh * SEQ * DHEAD;
  const short* Vt = vtb + bh * DHEAD * SEQ;

  bf16x8 qf[4][2];
  #pragma unroll
  for (int f = 0; f < 4; ++f) {
    qf[f][0] = *(const bf16x8*)&Q[(mF[f] + l16) * DHEAD + quad * 8];
    qf[f][1] = *(const bf16x8*)&Q[(mF[f] + l16) * DHEAD + 32 + quad * 8];
  }

  float lF[4] = {};
  f32x4 oF[4][4] = {};

  const int vdl = lane >> 3, vsl = lane & 7;        // V staging lane split

  auto stage1 = [&](int buf, int slot, int t0) {    // one 64-t chunk
    #pragma unroll
    for (int j = 0; j < 2; ++j) {
      int g = j * 4 + wave;                         // K ch-group 0..7
      const short* gp = Kp + (t0 + lane) * DHEAD + g * 8;
      __builtin_amdgcn_global_load_lds((__attribute__((address_space(1))) void*)gp,
                                       (__attribute__((address_space(3))) void*)&kls[buf][slot * 4096 + g * 512],
                                       16, 0, 0);
    }
    #pragma unroll
    for (int j = 0; j < 2; ++j) {
      int gd = j * 4 + wave;                        // V d-block 0..7
      const short* gp = Vt + (gd * 8 + vdl) * SEQ + t0 + ((vsl ^ vdl) * 8);
      __builtin_amdgcn_global_load_lds((__attribute__((address_space(1))) void*)gp,
                                       (__attribute__((address_space(3))) void*)&vls[buf][slot * 4096 + gd * 512],
                                       16, 0, 0);
    }
  };
  auto stagepair = [&](int buf, int cc) {           // chunks cc, cc+2 (owned set)
    stage1(buf, 0, cc * 64);
    if (cc + 2 < nch) stage1(buf, 1, (cc + 2) * 64);
  };

  stagepair(0, half);
  int it = 0;
  for (int cc = half; cc < nch; cc += 4, ++it) {
    __syncthreads();                                // drains stagepair; waves synced
    if (cc + 4 < nch) stagepair((it + 1) & 1, cc + 4);
    const int buf = it & 1;
    #pragma unroll
    for (int u = 0; u < 2; ++u) {                   // chunk within pair
      const int c = cc + 2 * u;
      if (c < nch) {                                // block-uniform
        const int t0 = c * 64;
        const int sb = u * 4096;
        #pragma unroll
        for (int t = 0; t < 4; ++t) {
          const int tb = t0 + t * 16;
          if (tb <= mF[3]) {                        // any fragment live (wave-uniform)
            bf16x8 kf0 = *(const bf16x8*)&kls[buf][sb + ((0 + quad) * 64 + t * 16 + l16) * 8];
            bf16x8 kf1 = *(const bf16x8*)&kls[buf][sb + ((4 + quad) * 64 + t * 16 + l16) * 8];
            s16x4 vf[4];
            {
              int gsw = ((t * 2 + (quad >> 1)) ^ (l16 & 7));
              #pragma unroll
              for (int dt = 0; dt < 4; ++dt)
                vf[dt] = *(const s16x4*)&vls[buf][sb + ((dt * 16 + l16) * 8 + gsw) * 8 + (quad & 1) * 4];
            }
            #pragma unroll
            for (int f = 0; f < 4; ++f) {
              if (tb <= mF[f]) {                    // wave-uniform
                f32x4 a = {};
                a = __builtin_amdgcn_mfma_f32_16x16x32_bf16(kf0, qf[f][0], a, 0, 0, 0);
                a = __builtin_amdgcn_mfma_f32_16x16x32_bf16(kf1, qf[f][1], a, 0, 0, 0);
                if (tb == mF[f]) {                  // diagonal: mask t > m
                  #pragma unroll
                  for (int r = 0; r < 4; ++r)
                    if (quad * 4 + r > l16) a[r] = -1e30f;
                }
                f32x4 p;
                #pragma unroll
                for (int r = 0; r < 4; ++r) p[r] = __builtin_amdgcn_exp2f(a[r]);
                lF[f] += (p[0] + p[1]) + (p[2] + p[3]);
                __hip_bfloat162 c01 = __float22bfloat162_rn(float2{p[0], p[1]});
                __hip_bfloat162 c23 = __float22bfloat162_rn(float2{p[2], p[3]});
                union { unsigned u2[2]; s16x4 s; } pu;
                pu.u2[0] = *(unsigned*)&c01; pu.u2[1] = *(unsigned*)&c23;
                #pragma unroll
                for (int dt = 0; dt < 4; ++dt)
                  oF[f][dt] = __builtin_amdgcn_mfma_f32_16x16x16bf16_1k(pu.s, vf[dt], oF[f][dt], 0, 0, 0);
              }
            }
          }
        }
      }
    }
  }

  // reduce l across quads; store partials [half][bh][s][64]
  float* lD = lP + (half * NBH + bh) * SEQ;
  short* oD = oP + ((half * NBH + bh) * SEQ) * DHEAD;
  #pragma unroll
  for (int f = 0; f < 4; ++f) {
    float l = lF[f];
    l += __shfl_xor(l, 16, 64); l += __shfl_xor(l, 32, 64);
    if (quad == 0) lD[mF[f] + l16] = l;
    #pragma unroll
    for (int r = 0; r < 4; ++r) {
      int s = mF[f] + quad * 4 + r;
      #pragma unroll
      for (int dt = 0; dt < 4; ++dt)
        oD[s * DHEAD + dt * 16 + l16] = f2bf(oF[f][dt][r]);
    }
  }
}

// ---------- merge halves: ob = (oE + oO) / (lE + lO), bf16 [b][s][h*64+d] ----
__global__ void attn_merge(const short* __restrict__ oP, const float* __restrict__ lP,
                           short* __restrict__ ob) {
  int idx = blockIdx.x * 256 + threadIdx.x;         // one thread = 8 outputs
  int d8 = idx & 7, s = (idx >> 3) & (SEQ - 1), bh = idx >> 14;
  s16x8 e = *(const s16x8*)&oP[((0   + bh) * SEQ + s) * DHEAD + d8 * 8];
  s16x8 o = *(const s16x8*)&oP[((NBH + bh) * SEQ + s) * DHEAD + d8 * 8];
  float linv = 1.0f / (lP[bh * SEQ + s] + lP[(NBH + bh) * SEQ + s]);
  s16x8 r;
  #pragma unroll
  for (int k = 0; k < 8; ++k) r[k] = f2bf((bf2f(e[k]) + bf2f(o[k])) * linv);
  int b = bh >> 4, h = bh & 15;
  *(s16x8*)&ob[(b * SEQ + s) * DMODEL + h * DHEAD + d8 * 8] = r;
}

extern "C" void kernel_launch(void* const* d_in, const int* in_sizes, int n_in,
                              void* d_out, int out_size, void* d_ws, size_t ws_size,
                              hipStream_t stream) {
  const float* x  = (const float*)d_in[0];
  const float* Wq = (const float*)d_in[1];
  const float* bq = (const float*)d_in[2];
  const float* Wk = (const float*)d_in[3];
  const float* bk = (const float*)d_in[4];
  const float* Wv = (const float*)d_in[5];
  const float* bv = (const float*)d_in[6];
  const float* Wo = (const float*)d_in[7];
  float* out = (float*)d_out;

  char* ws = (char*)d_ws;                         // ws is 256 MB (measured R7)
  short* xb  = (short*)(ws);                      // 8 MB  x bf16
  short* wtq = (short*)(ws + (8u  << 20));        // 6 MB  [Wq^T;Wk^T;Wv^T] bf16
  short* wto = (short*)(ws + (14u << 20));        // 2 MB  Wo^T bf16
  short* qb  = (short*)(ws + (16u << 20));        // 8 MB  Q (x 0.125*log2e folded)
  short* kb  = (short*)(ws + (24u << 20));        // 8 MB  K
  short* vt  = (short*)(ws + (32u << 20));        // 8 MB  V^T [bh][d][s]
  short* ob  = (short*)(ws + (40u << 20));        // 8 MB  attn out bf16
  short* oP  = (short*)(ws + (48u << 20));        // 16 MB o-partials [2][32][2048][64]
  float* lP  = (float*)(ws + (80u << 20));        // 0.5MB l-partials [2][32][2048]

  prep_fused<<<dim3(32, 32, 8), dim3(32, 8), 0, stream>>>(x, xb, Wq, Wk, Wv, Wo, wtq, wto);

  gemm_bf16<128, 128, 0><<<dim3(3 * DMODEL / 128, MROWS / 128), 256, 0, stream>>>(
      xb, wtq, bq, bk, bv, qb, kb, vt, nullptr);

  attn_k<<<8 * NBH * 2, 256, 0, stream>>>(qb, kb, vt, oP, lP);
  attn_merge<<<NBH * SEQ * 8 / 256, 256, 0, stream>>>(oP, lP, ob);

  gemm_bf16<64, 128, 1><<<dim3(DMODEL / 128, MROWS / 64), 256, 0, stream>>>(
      ob, wto, nullptr, nullptr, nullptr, nullptr, nullptr, nullptr, out);
}